// Round 2
// baseline (403.271 us; speedup 1.0000x reference)
//
#include <hip/hip_runtime.h>
#include <hip/hip_bf16.h>

#define N 8192
#define FIN 128
#define FOUT 64
#define ALPHA 0.2f
#define LOG2E 1.44269504f
#define JSPAN N               // single block covers the full j range
#define STJ 256               // j per stage = 8 units of 32
#define NST (JSPAN / STJ)     // 32 stages

typedef __attribute__((ext_vector_type(8))) short short8;
typedef __attribute__((ext_vector_type(4))) float f32x4;

static __device__ __forceinline__ unsigned fkey(float x) {
    unsigned u = __float_as_uint(x);
    return (u >> 31) ? ~u : (u | 0x80000000u);
}
static __device__ __forceinline__ float fdecode(unsigned k) {
    unsigned u = (k & 0x80000000u) ? (k & 0x7FFFFFFFu) : ~k;
    return __uint_as_float(u);
}
// async global->LDS DMA: per-lane 16B gather; LDS dest = wave-uniform base + lane*16.
static __device__ __forceinline__ void gll16(const float* g, float* l) {
    __builtin_amdgcn_global_load_lds(
        (const __attribute__((address_space(1))) unsigned int*)g,
        (__attribute__((address_space(3))) unsigned int*)l, 16, 0, 0);
}

// ---------------- k_prep: Wh = h@W; s2 = (Wh@a1)*log2e; t2 = (Wh@a2)*log2e --------
__global__ __launch_bounds__(256) void k_prep(const float* __restrict__ h,
                                              const float* __restrict__ W,
                                              const float* __restrict__ a,
                                              float* __restrict__ Wh,
                                              float* __restrict__ s2,
                                              float* __restrict__ t2,
                                              unsigned* __restrict__ keys) {
    __shared__ float lH[16 * FIN];
    __shared__ float lW[FIN * FOUT];
    __shared__ float red[8];
    const int tid = threadIdx.x;
    const int r0 = blockIdx.x * 16;
    {
        const float4* src = (const float4*)(h + (size_t)r0 * FIN);
        float4* dst = (float4*)lH;
        for (int i = tid; i < 16 * FIN / 4; i += 256) dst[i] = src[i];
        const float4* ws_ = (const float4*)W;
        float4* dw = (float4*)lW;
        for (int i = tid; i < FIN * FOUT / 4; i += 256) dw[i] = ws_[i];
    }
    __syncthreads();
    const int wave = tid >> 6, lane = tid & 63;
    float acc[4] = {0.f, 0.f, 0.f, 0.f};
    for (int k = 0; k < FIN; ++k) {
        float wv = lW[k * FOUT + lane];
#pragma unroll
        for (int r = 0; r < 4; ++r)
            acc[r] = fmaf(lH[(wave * 4 + r) * FIN + k], wv, acc[r]);
    }
    const float a1 = a[lane], a2 = a[FOUT + lane];
    float smx = -1e30f, tmx = -1e30f;
#pragma unroll
    for (int r = 0; r < 4; ++r) {
        int row = r0 + wave * 4 + r;
        Wh[(size_t)row * FOUT + lane] = acc[r];
        float sv = acc[r] * a1, tv = acc[r] * a2;
#pragma unroll
        for (int off = 32; off; off >>= 1) {
            sv += __shfl_xor(sv, off);
            tv += __shfl_xor(tv, off);
        }
        sv *= LOG2E; tv *= LOG2E;      // pre-scale: exp(x) -> exp2(x')
        if (lane == 0) { s2[row] = sv; t2[row] = tv; }
        smx = fmaxf(smx, sv);
        tmx = fmaxf(tmx, tv);
    }
    if (lane == 0) { red[wave] = smx; red[4 + wave] = tmx; }
    __syncthreads();
    if (tid == 0) {
        float ms = fmaxf(fmaxf(red[0], red[1]), fmaxf(red[2], red[3]));
        float mt = fmaxf(fmaxf(red[4], red[5]), fmaxf(red[6], red[7]));
        atomicMax(keys + 0, fkey(ms));
        atomicMax(keys + 1, fkey(mt));
    }
}

// ---------------- k_pack: Wh fp32 -> bf16 B-fragment layout ------------------------
// B-frag (16x16x32): lane holds col n = lane&15, k = (lane>>4)*8 + e
__global__ __launch_bounds__(256) void k_pack(const float* __restrict__ Wh,
                                              __hip_bfloat16* __restrict__ WhB) {
    const int c = blockIdx.x;
    const int tn = threadIdx.x >> 6;
    const int lane = threadIdx.x & 63;
    const int quad = lane >> 4, l16 = lane & 15;
    const float* src = Wh + ((size_t)(c * 32 + quad * 8)) * FOUT + tn * 16 + l16;
    union { unsigned short u[8]; short8 v; } frag;
#pragma unroll
    for (int e = 0; e < 8; ++e) {
        __hip_bfloat16 b = __float2bfloat16(src[(size_t)e * FOUT]);
        frag.u[e] = *(unsigned short*)&b;
    }
    *(short8*)&WhB[(((size_t)c * 4 + tn) * 64 + lane) * 8] = frag.v;
}

// ---------------- k_attn: fused mask+softmax+PV+ELU, barrier-free main loop --------
// Grid N/16 = 512 blocks; block 256 thr = 4 waves owns 16 rows x ALL 8192 j.
// Wave w stages AND computes units {2w, 2w+1} only -> no cross-wave data sharing in
// the main loop -> per-stage __syncthreads replaced by per-wave counted vmcnt:
//   per stage issue [8 B-frag loads][4 DMA(st+1)] then s_waitcnt vmcnt(12)
//   (outstanding = DMA(st)4 + B(st)8 + DMA(st+1)4 = 16 -> <=12 retires DMA(st);
//    the compiler's own B-wait vmcnt(4) leaves DMA(st+1) in flight).
__global__ __launch_bounds__(256) void k_attn(const float* __restrict__ adj,
                                              const __hip_bfloat16* __restrict__ WhB,
                                              const float* __restrict__ s2,
                                              const float* __restrict__ t2,
                                              const unsigned* __restrict__ keys,
                                              float* __restrict__ out) {
    __shared__ float bufA[2][8 * 512];   // 2 x 16 KB adj stages; [0] reused in epilogue
    __shared__ float tl[JSPAN];          // 32 KB t values (read-only after init)
    __shared__ float sred[64];           // per-wave row sums (NOT tl: waves decouple)
    const int wave = threadIdx.x >> 6, lane = threadIdx.x & 63;
    const int quad = lane >> 4, l16 = lane & 15;
    const int i0 = blockIdx.x * 16;
    const int u0 = 2 * wave;

    // prologue: DMA stage 0 first (in flight under the tl staging)
    const float* gaw = adj + (size_t)(i0 + l16) * N + quad * 8;
    gll16(gaw + u0 * 32,      &bufA[0][u0 * 512]);
    gll16(gaw + u0 * 32 + 4,  &bufA[0][u0 * 512 + 256]);
    gll16(gaw + u0 * 32 + 32, &bufA[0][(u0 + 1) * 512]);
    gll16(gaw + u0 * 32 + 36, &bufA[0][(u0 + 1) * 512 + 256]);

    // t2 -> LDS (one-time)
    {
        const float4* src = (const float4*)t2;
        float4* dst = (float4*)tl;
        for (int i = threadIdx.x; i < JSPAN / 4; i += 256) dst[i] = src[i];
    }
    const float mraw = fdecode(keys[0]) + fdecode(keys[1]);
    const float mm = mraw > 0.f ? mraw : ALPHA * mraw;
    const float sm = s2[i0 + l16];
    const short8* BF = (const short8*)WhB;

    f32x4 acc0 = {0,0,0,0}, acc1 = {0,0,0,0}, acc2 = {0,0,0,0}, acc3 = {0,0,0,0};
    float lsum = 0.f;
    __syncthreads();   // tl visible; drains prologue loads (loop accounting holds)

    for (int st = 0; st < NST; ++st) {
        const int b = st & 1;
        // (1) B-fragments for this stage's two units — issued FIRST so their
        //     waitcnt leaves the (newer) next-stage DMA outstanding.
        const size_t kc = (size_t)(st * 8 + u0) * 4;
        short8 B00 = BF[(kc + 0) * 64 + lane];
        short8 B01 = BF[(kc + 1) * 64 + lane];
        short8 B02 = BF[(kc + 2) * 64 + lane];
        short8 B03 = BF[(kc + 3) * 64 + lane];
        short8 B10 = BF[(kc + 4) * 64 + lane];
        short8 B11 = BF[(kc + 5) * 64 + lane];
        short8 B12 = BF[(kc + 6) * 64 + lane];
        short8 B13 = BF[(kc + 7) * 64 + lane];
        __builtin_amdgcn_sched_barrier(0);   // pin: B loads before DMA
        // (2) DMA next stage's adj, then wait for THIS stage's DMA only
        if (st + 1 < NST) {
            const float* g = gaw + (st + 1) * STJ + u0 * 32;
            float* d = &bufA[b ^ 1][u0 * 512];
            gll16(g, d);
            gll16(g + 4, d + 256);
            gll16(g + 32, d + 512);
            gll16(g + 36, d + 768);
            __builtin_amdgcn_sched_barrier(0);
            asm volatile("s_waitcnt vmcnt(12)" ::: "memory");
        } else {
            asm volatile("s_waitcnt vmcnt(8)" ::: "memory");
        }
        __builtin_amdgcn_sched_barrier(0);   // rule #18: fence LDS reads below the wait
        // (3) compute units u0, u0+1 from bufA[b]
#pragma unroll
        for (int uu = 0; uu < 2; ++uu) {
            const int ul = u0 + uu;
            const float* Au = &bufA[b][ul * 512];
            float4 alo = *(const float4*)(Au + lane * 4);
            float4 ahi = *(const float4*)(Au + 256 + lane * 4);
            const float* Tp = tl + st * STJ + ul * 32 + quad * 8;
            float4 tlo = *(const float4*)Tp;
            float4 thi = *(const float4*)(Tp + 4);
            union { __hip_bfloat162 h2[4]; short8 v; } af;
#pragma unroll
            for (int pp = 0; pp < 4; ++pp) {
                float a0 = (pp < 2) ? ((const float*)&alo)[2 * pp]     : ((const float*)&ahi)[2 * pp - 4];
                float a1 = (pp < 2) ? ((const float*)&alo)[2 * pp + 1] : ((const float*)&ahi)[2 * pp - 3];
                float t0 = (pp < 2) ? ((const float*)&tlo)[2 * pp]     : ((const float*)&thi)[2 * pp - 4];
                float t1 = (pp < 2) ? ((const float*)&tlo)[2 * pp + 1] : ((const float*)&thi)[2 * pp - 3];
                float x0 = sm + t0,                x1 = sm + t1;
                float le0 = fmaxf(x0, ALPHA * x0), le1 = fmaxf(x1, ALPHA * x1);
                float p0 = a0 * exp2f(le0 - mm),   p1 = a1 * exp2f(le1 - mm);
                __hip_bfloat162 pb = __float22bfloat162_rn(make_float2(p0, p1));
                af.h2[pp] = pb;
                lsum += __bfloat162float(pb.x) + __bfloat162float(pb.y);
            }
            if (uu == 0) {
                acc0 = __builtin_amdgcn_mfma_f32_16x16x32_bf16(af.v, B00, acc0, 0, 0, 0);
                acc1 = __builtin_amdgcn_mfma_f32_16x16x32_bf16(af.v, B01, acc1, 0, 0, 0);
                acc2 = __builtin_amdgcn_mfma_f32_16x16x32_bf16(af.v, B02, acc2, 0, 0, 0);
                acc3 = __builtin_amdgcn_mfma_f32_16x16x32_bf16(af.v, B03, acc3, 0, 0, 0);
            } else {
                acc0 = __builtin_amdgcn_mfma_f32_16x16x32_bf16(af.v, B10, acc0, 0, 0, 0);
                acc1 = __builtin_amdgcn_mfma_f32_16x16x32_bf16(af.v, B11, acc1, 0, 0, 0);
                acc2 = __builtin_amdgcn_mfma_f32_16x16x32_bf16(af.v, B12, acc2, 0, 0, 0);
                acc3 = __builtin_amdgcn_mfma_f32_16x16x32_bf16(af.v, B13, acc3, 0, 0, 0);
            }
        }
        // no barrier: each wave owns its bufA units; counted vmcnt paces the pipeline
    }

    // lsum: lanes {m, m+16, m+32, m+48} hold row-m partials for this wave's units
    lsum += __shfl_xor(lsum, 16);
    lsum += __shfl_xor(lsum, 32);

    // epilogue: wave w writes its OWN bufA[0] region [1024w, 1024w+1024) — safe
    // even while other waves still run; cross-wave reads gated by the barrier.
    float* accr = &bufA[0][0];
    *(f32x4*)&accr[((wave * 4 + 0) * 64 + lane) * 4] = acc0;
    *(f32x4*)&accr[((wave * 4 + 1) * 64 + lane) * 4] = acc1;
    *(f32x4*)&accr[((wave * 4 + 2) * 64 + lane) * 4] = acc2;
    *(f32x4*)&accr[((wave * 4 + 3) * 64 + lane) * 4] = acc3;
    if (lane < 16) sred[wave * 16 + lane] = lsum;
    __syncthreads();

    const int tile = wave;
    f32x4 tot = {0, 0, 0, 0};
#pragma unroll
    for (int w = 0; w < 4; ++w) {
        f32x4 c = *(const f32x4*)&accr[((w * 4 + tile) * 64 + lane) * 4];
        tot[0] += c[0]; tot[1] += c[1]; tot[2] += c[2]; tot[3] += c[3];
    }
#pragma unroll
    for (int r = 0; r < 4; ++r) {
        int row = quad * 4 + r;  // C/D: row=(lane>>4)*4+reg, col=l16 within tile
        float lv = sred[row] + sred[16 + row] + sred[32 + row] + sred[48 + row];
        float v = tot[r] / lv;
        out[(size_t)(i0 + row) * FOUT + tile * 16 + l16] =
            v > 0.f ? v : (exp2f(v * LOG2E) - 1.f);
    }
}

extern "C" void kernel_launch(void* const* d_in, const int* in_sizes, int n_in,
                              void* d_out, int out_size, void* d_ws, size_t ws_size,
                              hipStream_t stream) {
    const float* h   = (const float*)d_in[0];
    const float* adj = (const float*)d_in[1];
    const float* W   = (const float*)d_in[2];
    const float* a   = (const float*)d_in[3];
    float* out = (float*)d_out;

    char* base = (char*)d_ws;
    float* Wh = (float*)base;                        base += (size_t)N * FOUT * 4;
    __hip_bfloat16* WhB = (__hip_bfloat16*)base;     base += (size_t)N * FOUT * 2;
    float* s2 = (float*)base;                        base += (size_t)N * 4;
    float* t2 = (float*)base;                        base += (size_t)N * 4 + 1024;
    unsigned* keys = (unsigned*)base;

    hipMemsetAsync(keys, 0, 2 * sizeof(unsigned), stream);
    k_prep<<<N / 16, 256, 0, stream>>>(h, W, a, Wh, s2, t2, keys);
    k_pack<<<N / 32, 256, 0, stream>>>(Wh, WhB);
    k_attn<<<N / 16, 256, 0, stream>>>(adj, WhB, s2, t2, keys, out);
}

// Round 3
// 398.457 us; speedup vs baseline: 1.0121x; 1.0121x over previous
//
#include <hip/hip_runtime.h>
#include <hip/hip_bf16.h>

#define N 8192
#define FIN 128
#define FOUT 64
#define ALPHA 0.2f
#define LOG2E 1.44269504f
#define STJ 256               // j per stage = 8 units of 32
#define NST (N / STJ)         // 32 stages

typedef __attribute__((ext_vector_type(8))) short short8;
typedef __attribute__((ext_vector_type(4))) float f32x4;

static __device__ __forceinline__ unsigned fkey(float x) {
    unsigned u = __float_as_uint(x);
    return (u >> 31) ? ~u : (u | 0x80000000u);
}
static __device__ __forceinline__ float fdecode(unsigned k) {
    unsigned u = (k & 0x80000000u) ? (k & 0x7FFFFFFFu) : ~k;
    return __uint_as_float(u);
}
// async global->LDS DMA: per-lane 16B gather; LDS dest = wave-uniform base + lane*16.
static __device__ __forceinline__ void gll16(const float* g, float* l) {
    __builtin_amdgcn_global_load_lds(
        (const __attribute__((address_space(1))) unsigned int*)g,
        (__attribute__((address_space(3))) unsigned int*)l, 16, 0, 0);
}

// ---------------- k_prep: Wh = h@W fused with bf16 B-frag pack + s2/t2/keys -------
// 256 blocks x 32 rows. Wave w owns rows w*8..w*8+7, lane l owns col l.
// Thread (w,l) holds Wh[r0+w*8+e][l] -> exactly one B-frag short8:
//   frag idx = ((c*4 + (l>>4))*64 + (w*16 + (l&15))), elements e=0..7.
__global__ __launch_bounds__(256) void k_prep(const float* __restrict__ h,
                                              const float* __restrict__ W,
                                              const float* __restrict__ a,
                                              __hip_bfloat16* __restrict__ WhB,
                                              float* __restrict__ s2,
                                              float* __restrict__ t2,
                                              unsigned* __restrict__ keys) {
    __shared__ float lH[32 * FIN];    // 16 KB
    __shared__ float lW[FIN * FOUT];  // 32 KB
    __shared__ float red[8];
    const int tid = threadIdx.x;
    const int c = blockIdx.x;
    const int r0 = c * 32;
    {
        const float4* src = (const float4*)(h + (size_t)r0 * FIN);
        float4* dst = (float4*)lH;
        for (int i = tid; i < 32 * FIN / 4; i += 256) dst[i] = src[i];
        const float4* ws_ = (const float4*)W;
        float4* dw = (float4*)lW;
        for (int i = tid; i < FIN * FOUT / 4; i += 256) dw[i] = ws_[i];
    }
    __syncthreads();
    const int wave = tid >> 6, lane = tid & 63;
    float acc[8] = {0.f, 0.f, 0.f, 0.f, 0.f, 0.f, 0.f, 0.f};
#pragma unroll 4
    for (int k = 0; k < FIN; ++k) {
        float wv = lW[k * FOUT + lane];
#pragma unroll
        for (int r = 0; r < 8; ++r)
            acc[r] = fmaf(lH[(wave * 8 + r) * FIN + k], wv, acc[r]);
    }
    // direct B-frag store (replaces k_pack + the Wh fp32 round-trip)
    union { unsigned short u[8]; short8 v; } frag;
#pragma unroll
    for (int e = 0; e < 8; ++e) {
        __hip_bfloat16 b = __float2bfloat16(acc[e]);
        frag.u[e] = *(unsigned short*)&b;
    }
    *(short8*)&WhB[(((size_t)c * 4 + (lane >> 4)) * 64 + (wave * 16 + (lane & 15))) * 8] = frag.v;

    const float a1 = a[lane], a2 = a[FOUT + lane];
    float smx = -1e30f, tmx = -1e30f;
#pragma unroll
    for (int r = 0; r < 8; ++r) {
        int row = r0 + wave * 8 + r;
        float sv = acc[r] * a1, tv = acc[r] * a2;
#pragma unroll
        for (int off = 32; off; off >>= 1) {
            sv += __shfl_xor(sv, off);
            tv += __shfl_xor(tv, off);
        }
        sv *= LOG2E; tv *= LOG2E;      // pre-scale: exp(x) -> exp2(x')
        if (lane == 0) { s2[row] = sv; t2[row] = tv; }
        smx = fmaxf(smx, sv);
        tmx = fmaxf(tmx, tv);
    }
    if (lane == 0) { red[wave] = smx; red[4 + wave] = tmx; }
    __syncthreads();
    if (tid == 0) {
        float ms = fmaxf(fmaxf(red[0], red[1]), fmaxf(red[2], red[3]));
        float mt = fmaxf(fmaxf(red[4], red[5]), fmaxf(red[6], red[7]));
        atomicMax(keys + 0, fkey(ms));
        atomicMax(keys + 1, fkey(mt));
    }
}

// ---------------- k_attn: fused mask+softmax+PV+ELU, 2-deep prefetch -------------
// Grid 512 blocks x 4 waves; wave w owns units {2w,2w+1} of every stage (no cross-
// wave sharing in the main loop -> barrier-free). Triple-buffered adj in LDS.
// FIFO vmcnt: DMA(st+1) survives stage-st compute only if issued AFTER B(st), so
// B-frags and t-values are software-pipelined one stage ahead (group F = 8B + 4t):
//   stream per iter: F(st+1)[12], DMA(st+2)[4], wait vmcnt(32) for DMA(st)
//   (newer-than-DMA(st) = F(st)12 + DMA(st+1)4 + F(st+1)12 + DMA(st+2)4 = 32;
//    tails: 28 at st=NST-2, 12 at st=NST-1). Compiler's F(st)-use wait = vmcnt(20)
//   keeps DMA(st+1), F(st+1), DMA(st+2) all in flight -> ~8 KB adj/wave in flight.
__global__ __launch_bounds__(256) void k_attn(const float* __restrict__ adj,
                                              const __hip_bfloat16* __restrict__ WhB,
                                              const float* __restrict__ s2,
                                              const float* __restrict__ t2,
                                              const unsigned* __restrict__ keys,
                                              float* __restrict__ out) {
    __shared__ float bufA[3][8 * 512];   // 3 x 16 KB adj stages; [0] reused in epilogue
    __shared__ float sred[64];           // per-wave row sums
    const int wave = threadIdx.x >> 6, lane = threadIdx.x & 63;
    const int quad = lane >> 4, l16 = lane & 15;
    const int i0 = blockIdx.x * 16;
    const int u0 = 2 * wave;

    // scalar-ish prologue loads; force-drain so the counted vmcnt stream is clean
    const float sm = s2[i0 + l16];
    const float mraw = fdecode(keys[0]) + fdecode(keys[1]);
    const float mm = mraw > 0.f ? mraw : ALPHA * mraw;
    asm volatile("" :: "v"(sm), "v"(mm));
    __builtin_amdgcn_sched_barrier(0);

    const float* gawu = adj + (size_t)(i0 + l16) * N + quad * 8 + u0 * 32;
    const short8* BF = (const short8*)WhB;

    // ---- prologue: DMA(0); F(0); DMA(1) ----
    gll16(gawu,      &bufA[0][u0 * 512]);
    gll16(gawu + 4,  &bufA[0][u0 * 512 + 256]);
    gll16(gawu + 32, &bufA[0][(u0 + 1) * 512]);
    gll16(gawu + 36, &bufA[0][(u0 + 1) * 512 + 256]);
    __builtin_amdgcn_sched_barrier(0);
    size_t kc = (size_t)u0 * 4;
    short8 B0 = BF[(kc + 0) * 64 + lane];
    short8 B1 = BF[(kc + 1) * 64 + lane];
    short8 B2 = BF[(kc + 2) * 64 + lane];
    short8 B3 = BF[(kc + 3) * 64 + lane];
    short8 B4 = BF[(kc + 4) * 64 + lane];
    short8 B5 = BF[(kc + 5) * 64 + lane];
    short8 B6 = BF[(kc + 6) * 64 + lane];
    short8 B7 = BF[(kc + 7) * 64 + lane];
    const float* Tp = t2 + u0 * 32 + quad * 8;
    float4 T0 = *(const float4*)Tp;
    float4 T1 = *(const float4*)(Tp + 4);
    float4 T2v = *(const float4*)(Tp + 32);
    float4 T3v = *(const float4*)(Tp + 36);
    __builtin_amdgcn_sched_barrier(0);
    gll16(gawu + STJ,      &bufA[1][u0 * 512]);
    gll16(gawu + STJ + 4,  &bufA[1][u0 * 512 + 256]);
    gll16(gawu + STJ + 32, &bufA[1][(u0 + 1) * 512]);
    gll16(gawu + STJ + 36, &bufA[1][(u0 + 1) * 512 + 256]);
    __builtin_amdgcn_sched_barrier(0);

    f32x4 acc0 = {0,0,0,0}, acc1 = {0,0,0,0}, acc2 = {0,0,0,0}, acc3 = {0,0,0,0};
    float lsum = 0.f;
    int bi = 0;   // buffer holding stage st

    for (int st = 0; st < NST; ++st) {
        const bool hasN = (st + 1 < NST);
        // (1) F(st+1): next stage's B-frags + t-values
        short8 nB0, nB1, nB2, nB3, nB4, nB5, nB6, nB7;
        float4 nT0, nT1, nT2, nT3;
        if (hasN) {
            const size_t nkc = (size_t)((st + 1) * 8 + u0) * 4;
            nB0 = BF[(nkc + 0) * 64 + lane];
            nB1 = BF[(nkc + 1) * 64 + lane];
            nB2 = BF[(nkc + 2) * 64 + lane];
            nB3 = BF[(nkc + 3) * 64 + lane];
            nB4 = BF[(nkc + 4) * 64 + lane];
            nB5 = BF[(nkc + 5) * 64 + lane];
            nB6 = BF[(nkc + 6) * 64 + lane];
            nB7 = BF[(nkc + 7) * 64 + lane];
            const float* nTp = t2 + (st + 1) * STJ + u0 * 32 + quad * 8;
            nT0 = *(const float4*)nTp;
            nT1 = *(const float4*)(nTp + 4);
            nT2 = *(const float4*)(nTp + 32);
            nT3 = *(const float4*)(nTp + 36);
        }
        __builtin_amdgcn_sched_barrier(0);   // pin: F before DMA
        // (2) DMA(st+2)
        if (st + 2 < NST) {
            const float* g = gawu + (st + 2) * STJ;
            const int di = bi >= 1 ? bi - 1 : 2;   // (st+2)%3
            float* d = &bufA[di][u0 * 512];
            gll16(g, d);
            gll16(g + 4, d + 256);
            gll16(g + 32, d + 512);
            gll16(g + 36, d + 768);
        }
        __builtin_amdgcn_sched_barrier(0);   // pin: DMA before wait
        // (3) wait for DMA(st) only (FIFO retirement => counts are exact)
        if (st < NST - 2)       asm volatile("s_waitcnt vmcnt(32)" ::: "memory");
        else if (st == NST - 2) asm volatile("s_waitcnt vmcnt(28)" ::: "memory");
        else                    asm volatile("s_waitcnt vmcnt(12)" ::: "memory");
        __builtin_amdgcn_sched_barrier(0);   // rule #18: fence LDS reads below the wait
        // (4) compute stage st from bufA[bi] + F(st)
#pragma unroll
        for (int uu = 0; uu < 2; ++uu) {
            const float* Au = &bufA[bi][(u0 + uu) * 512];
            float4 alo = *(const float4*)(Au + lane * 4);
            float4 ahi = *(const float4*)(Au + 256 + lane * 4);
            float4 tlo = uu ? T2v : T0;
            float4 thi = uu ? T3v : T1;
            union { __hip_bfloat162 h2[4]; short8 v; } af;
#pragma unroll
            for (int pp = 0; pp < 4; ++pp) {
                float a0 = (pp < 2) ? ((const float*)&alo)[2 * pp]     : ((const float*)&ahi)[2 * pp - 4];
                float a1 = (pp < 2) ? ((const float*)&alo)[2 * pp + 1] : ((const float*)&ahi)[2 * pp - 3];
                float t0 = (pp < 2) ? ((const float*)&tlo)[2 * pp]     : ((const float*)&thi)[2 * pp - 4];
                float t1 = (pp < 2) ? ((const float*)&tlo)[2 * pp + 1] : ((const float*)&thi)[2 * pp - 3];
                float x0 = sm + t0,                x1 = sm + t1;
                float le0 = fmaxf(x0, ALPHA * x0), le1 = fmaxf(x1, ALPHA * x1);
                float p0 = a0 * exp2f(le0 - mm),   p1 = a1 * exp2f(le1 - mm);
                __hip_bfloat162 pb = __float22bfloat162_rn(make_float2(p0, p1));
                af.h2[pp] = pb;
                lsum += __bfloat162float(pb.x) + __bfloat162float(pb.y);
            }
            if (uu == 0) {
                acc0 = __builtin_amdgcn_mfma_f32_16x16x32_bf16(af.v, B0, acc0, 0, 0, 0);
                acc1 = __builtin_amdgcn_mfma_f32_16x16x32_bf16(af.v, B1, acc1, 0, 0, 0);
                acc2 = __builtin_amdgcn_mfma_f32_16x16x32_bf16(af.v, B2, acc2, 0, 0, 0);
                acc3 = __builtin_amdgcn_mfma_f32_16x16x32_bf16(af.v, B3, acc3, 0, 0, 0);
            } else {
                acc0 = __builtin_amdgcn_mfma_f32_16x16x32_bf16(af.v, B4, acc0, 0, 0, 0);
                acc1 = __builtin_amdgcn_mfma_f32_16x16x32_bf16(af.v, B5, acc1, 0, 0, 0);
                acc2 = __builtin_amdgcn_mfma_f32_16x16x32_bf16(af.v, B6, acc2, 0, 0, 0);
                acc3 = __builtin_amdgcn_mfma_f32_16x16x32_bf16(af.v, B7, acc3, 0, 0, 0);
            }
        }
        // (5) rotate pipeline registers / buffer index
        if (hasN) {
            B0 = nB0; B1 = nB1; B2 = nB2; B3 = nB3;
            B4 = nB4; B5 = nB5; B6 = nB6; B7 = nB7;
            T0 = nT0; T1 = nT1; T2v = nT2; T3v = nT3;
        }
        bi = bi == 2 ? 0 : bi + 1;
    }

    // lsum: lanes {m, m+16, m+32, m+48} hold row-m partials for this wave's units
    lsum += __shfl_xor(lsum, 16);
    lsum += __shfl_xor(lsum, 32);

    // epilogue: wave w writes only its OWN bufA[0] region [w*1024, (w+1)*1024) —
    // disjoint from every other wave's reads at any stage => safe without drift bound.
    float* accr = &bufA[0][0];
    *(f32x4*)&accr[((wave * 4 + 0) * 64 + lane) * 4] = acc0;
    *(f32x4*)&accr[((wave * 4 + 1) * 64 + lane) * 4] = acc1;
    *(f32x4*)&accr[((wave * 4 + 2) * 64 + lane) * 4] = acc2;
    *(f32x4*)&accr[((wave * 4 + 3) * 64 + lane) * 4] = acc3;
    if (lane < 16) sred[wave * 16 + lane] = lsum;
    __syncthreads();

    const int tile = wave;
    f32x4 tot = {0, 0, 0, 0};
#pragma unroll
    for (int w = 0; w < 4; ++w) {
        f32x4 c = *(const f32x4*)&accr[((w * 4 + tile) * 64 + lane) * 4];
        tot[0] += c[0]; tot[1] += c[1]; tot[2] += c[2]; tot[3] += c[3];
    }
#pragma unroll
    for (int r = 0; r < 4; ++r) {
        int row = quad * 4 + r;  // C/D: row=(lane>>4)*4+reg, col=l16 within tile
        float lv = sred[row] + sred[16 + row] + sred[32 + row] + sred[48 + row];
        float v = tot[r] / lv;
        out[(size_t)(i0 + row) * FOUT + tile * 16 + l16] =
            v > 0.f ? v : (exp2f(v * LOG2E) - 1.f);
    }
}

extern "C" void kernel_launch(void* const* d_in, const int* in_sizes, int n_in,
                              void* d_out, int out_size, void* d_ws, size_t ws_size,
                              hipStream_t stream) {
    const float* h   = (const float*)d_in[0];
    const float* adj = (const float*)d_in[1];
    const float* W   = (const float*)d_in[2];
    const float* a   = (const float*)d_in[3];
    float* out = (float*)d_out;

    char* base = (char*)d_ws;
    __hip_bfloat16* WhB = (__hip_bfloat16*)base;     base += (size_t)N * FOUT * 2;
    float* s2 = (float*)base;                        base += (size_t)N * 4;
    float* t2 = (float*)base;                        base += (size_t)N * 4 + 1024;
    unsigned* keys = (unsigned*)base;

    hipMemsetAsync(keys, 0, 2 * sizeof(unsigned), stream);
    k_prep<<<N / 32, 256, 0, stream>>>(h, W, a, WhB, s2, t2, keys);
    k_attn<<<N / 16, 256, 0, stream>>>(adj, WhB, s2, t2, keys, out);
}

// Round 4
// 393.289 us; speedup vs baseline: 1.0254x; 1.0131x over previous
//
#include <hip/hip_runtime.h>
#include <hip/hip_bf16.h>

#define N 8192
#define FIN 128
#define FOUT 64
#define ALPHA 0.2f
#define LOG2E 1.44269504f
#define STJ 256               // j per stage = 8 units of 32
#define NST (N / STJ)         // 32 stages

typedef __attribute__((ext_vector_type(8))) short short8;
typedef __attribute__((ext_vector_type(4))) float f32x4;

static __device__ __forceinline__ unsigned fkey(float x) {
    unsigned u = __float_as_uint(x);
    return (u >> 31) ? ~u : (u | 0x80000000u);
}
static __device__ __forceinline__ float fdecode(unsigned k) {
    unsigned u = (k & 0x80000000u) ? (k & 0x7FFFFFFFu) : ~k;
    return __uint_as_float(u);
}

// ---------------- k_prep: Wh = h@W fused with bf16 B-frag pack + s2/t2/keys -------
// 256 blocks x 32 rows. Wave w owns rows w*8..w*8+7, lane l owns col l.
// Thread (w,l) holds Wh[r0+w*8+e][l] -> exactly one B-frag short8:
//   frag idx = ((c*4 + (l>>4))*64 + (w*16 + (l&15))), elements e=0..7.
__global__ __launch_bounds__(256) void k_prep(const float* __restrict__ h,
                                              const float* __restrict__ W,
                                              const float* __restrict__ a,
                                              __hip_bfloat16* __restrict__ WhB,
                                              float* __restrict__ s2,
                                              float* __restrict__ t2,
                                              unsigned* __restrict__ keys) {
    __shared__ float lH[32 * FIN];    // 16 KB
    __shared__ float lW[FIN * FOUT];  // 32 KB
    __shared__ float red[8];
    const int tid = threadIdx.x;
    const int c = blockIdx.x;
    const int r0 = c * 32;
    {
        const float4* src = (const float4*)(h + (size_t)r0 * FIN);
        float4* dst = (float4*)lH;
        for (int i = tid; i < 32 * FIN / 4; i += 256) dst[i] = src[i];
        const float4* ws_ = (const float4*)W;
        float4* dw = (float4*)lW;
        for (int i = tid; i < FIN * FOUT / 4; i += 256) dw[i] = ws_[i];
    }
    __syncthreads();
    const int wave = tid >> 6, lane = tid & 63;
    float acc[8] = {0.f, 0.f, 0.f, 0.f, 0.f, 0.f, 0.f, 0.f};
#pragma unroll 4
    for (int k = 0; k < FIN; ++k) {
        float wv = lW[k * FOUT + lane];
#pragma unroll
        for (int r = 0; r < 8; ++r)
            acc[r] = fmaf(lH[(wave * 8 + r) * FIN + k], wv, acc[r]);
    }
    // direct B-frag store (replaces k_pack + the Wh fp32 round-trip)
    union { unsigned short u[8]; short8 v; } frag;
#pragma unroll
    for (int e = 0; e < 8; ++e) {
        __hip_bfloat16 b = __float2bfloat16(acc[e]);
        frag.u[e] = *(unsigned short*)&b;
    }
    *(short8*)&WhB[(((size_t)c * 4 + (lane >> 4)) * 64 + (wave * 16 + (lane & 15))) * 8] = frag.v;

    const float a1 = a[lane], a2 = a[FOUT + lane];
    float smx = -1e30f, tmx = -1e30f;
#pragma unroll
    for (int r = 0; r < 8; ++r) {
        int row = r0 + wave * 8 + r;
        float sv = acc[r] * a1, tv = acc[r] * a2;
#pragma unroll
        for (int off = 32; off; off >>= 1) {
            sv += __shfl_xor(sv, off);
            tv += __shfl_xor(tv, off);
        }
        sv *= LOG2E; tv *= LOG2E;      // pre-scale: exp(x) -> exp2(x')
        if (lane == 0) { s2[row] = sv; t2[row] = tv; }
        smx = fmaxf(smx, sv);
        tmx = fmaxf(tmx, tv);
    }
    if (lane == 0) { red[wave] = smx; red[4 + wave] = tmx; }
    __syncthreads();
    if (tid == 0) {
        float ms = fmaxf(fmaxf(red[0], red[1]), fmaxf(red[2], red[3]));
        float mt = fmaxf(fmaxf(red[4], red[5]), fmaxf(red[6], red[7]));
        atomicMax(keys + 0, fkey(ms));
        atomicMax(keys + 1, fkey(mt));
    }
}

// ---------------- k_attn: fused mask+softmax+PV+ELU, all-register pipeline --------
// Grid 512 blocks x 4 waves; wave w owns units {2w,2w+1} of every stage. The adj
// path is PURE PASS-THROUGH per lane (lane reads back exactly the bytes it would
// DMA), so adj goes global->VGPR directly: 4x global_load_dwordx4 per stage per
// thread, software-pipelined 1 stage ahead together with the B-frag/t loads.
// No LDS in the main loop, no barriers, no hand-counted vmcnt — the compiler
// derives exact waits from register deps (B/T waits leave next-stage loads in
// flight). LDS only for the epilogue acc exchange (16.5 KB).
__global__ __launch_bounds__(256) void k_attn(const float* __restrict__ adj,
                                              const __hip_bfloat16* __restrict__ WhB,
                                              const float* __restrict__ s2,
                                              const float* __restrict__ t2,
                                              const unsigned* __restrict__ keys,
                                              float* __restrict__ out) {
    __shared__ float accr[16 * 256];     // 16 KB acc exchange (epilogue only)
    __shared__ float sred[64];           // per-wave row sums
    const int wave = threadIdx.x >> 6, lane = threadIdx.x & 63;
    const int quad = lane >> 4, l16 = lane & 15;
    const int i0 = blockIdx.x * 16;
    const int u0 = 2 * wave;

    const float sm = s2[i0 + l16];
    const float mraw = fdecode(keys[0]) + fdecode(keys[1]);
    const float mm = mraw > 0.f ? mraw : ALPHA * mraw;

    // lane's adj stream: row i0+l16, cols quad*8 + u*32 + st*256 (+0..7)
    const float* gA = adj + (size_t)(i0 + l16) * N + quad * 8 + u0 * 32;
    const short8* BF = (const short8*)WhB;

    // ---- prologue: stage-0 A-regs + B-frags + t-values ----
    float4 A00 = *(const float4*)(gA);
    float4 A01 = *(const float4*)(gA + 4);
    float4 A10 = *(const float4*)(gA + 32);
    float4 A11 = *(const float4*)(gA + 36);
    const size_t kc0 = (size_t)u0 * 4;
    short8 B0 = BF[(kc0 + 0) * 64 + lane];
    short8 B1 = BF[(kc0 + 1) * 64 + lane];
    short8 B2 = BF[(kc0 + 2) * 64 + lane];
    short8 B3 = BF[(kc0 + 3) * 64 + lane];
    short8 B4 = BF[(kc0 + 4) * 64 + lane];
    short8 B5 = BF[(kc0 + 5) * 64 + lane];
    short8 B6 = BF[(kc0 + 6) * 64 + lane];
    short8 B7 = BF[(kc0 + 7) * 64 + lane];
    const float* Tp = t2 + u0 * 32 + quad * 8;
    float4 T0  = *(const float4*)Tp;
    float4 T1  = *(const float4*)(Tp + 4);
    float4 T2v = *(const float4*)(Tp + 32);
    float4 T3v = *(const float4*)(Tp + 36);

    f32x4 acc0 = {0,0,0,0}, acc1 = {0,0,0,0}, acc2 = {0,0,0,0}, acc3 = {0,0,0,0};
    float lsum = 0.f;

    for (int st = 0; st < NST; ++st) {
        const bool hasN = (st + 1 < NST);
        // (1) prefetch next stage: adj A-regs first (longest latency), then B/T
        float4 nA00, nA01, nA10, nA11;
        short8 nB0, nB1, nB2, nB3, nB4, nB5, nB6, nB7;
        float4 nT0, nT1, nT2, nT3;
        if (hasN) {
            const float* g = gA + (st + 1) * STJ;
            nA00 = *(const float4*)(g);
            nA01 = *(const float4*)(g + 4);
            nA10 = *(const float4*)(g + 32);
            nA11 = *(const float4*)(g + 36);
            const size_t nkc = (size_t)((st + 1) * 8 + u0) * 4;
            nB0 = BF[(nkc + 0) * 64 + lane];
            nB1 = BF[(nkc + 1) * 64 + lane];
            nB2 = BF[(nkc + 2) * 64 + lane];
            nB3 = BF[(nkc + 3) * 64 + lane];
            nB4 = BF[(nkc + 4) * 64 + lane];
            nB5 = BF[(nkc + 5) * 64 + lane];
            nB6 = BF[(nkc + 6) * 64 + lane];
            nB7 = BF[(nkc + 7) * 64 + lane];
            const float* nTp = t2 + (st + 1) * STJ + u0 * 32 + quad * 8;
            nT0 = *(const float4*)nTp;
            nT1 = *(const float4*)(nTp + 4);
            nT2 = *(const float4*)(nTp + 32);
            nT3 = *(const float4*)(nTp + 36);
        }
        __builtin_amdgcn_sched_barrier(0);   // pin: all prefetch issues above compute
        // (2) compute stage st entirely from registers
#pragma unroll
        for (int uu = 0; uu < 2; ++uu) {
            float4 alo = uu ? A10 : A00;
            float4 ahi = uu ? A11 : A01;
            float4 tlo = uu ? T2v : T0;
            float4 thi = uu ? T3v : T1;
            union { __hip_bfloat162 h2[4]; short8 v; } af;
#pragma unroll
            for (int pp = 0; pp < 4; ++pp) {
                float a0 = (pp < 2) ? ((const float*)&alo)[2 * pp]     : ((const float*)&ahi)[2 * pp - 4];
                float a1 = (pp < 2) ? ((const float*)&alo)[2 * pp + 1] : ((const float*)&ahi)[2 * pp - 3];
                float t0 = (pp < 2) ? ((const float*)&tlo)[2 * pp]     : ((const float*)&thi)[2 * pp - 4];
                float t1 = (pp < 2) ? ((const float*)&tlo)[2 * pp + 1] : ((const float*)&thi)[2 * pp - 3];
                float x0 = sm + t0,                x1 = sm + t1;
                float le0 = fmaxf(x0, ALPHA * x0), le1 = fmaxf(x1, ALPHA * x1);
                float p0 = a0 * exp2f(le0 - mm),   p1 = a1 * exp2f(le1 - mm);
                __hip_bfloat162 pb = __float22bfloat162_rn(make_float2(p0, p1));
                af.h2[pp] = pb;
                lsum += __bfloat162float(pb.x) + __bfloat162float(pb.y);
            }
            if (uu == 0) {
                acc0 = __builtin_amdgcn_mfma_f32_16x16x32_bf16(af.v, B0, acc0, 0, 0, 0);
                acc1 = __builtin_amdgcn_mfma_f32_16x16x32_bf16(af.v, B1, acc1, 0, 0, 0);
                acc2 = __builtin_amdgcn_mfma_f32_16x16x32_bf16(af.v, B2, acc2, 0, 0, 0);
                acc3 = __builtin_amdgcn_mfma_f32_16x16x32_bf16(af.v, B3, acc3, 0, 0, 0);
            } else {
                acc0 = __builtin_amdgcn_mfma_f32_16x16x32_bf16(af.v, B4, acc0, 0, 0, 0);
                acc1 = __builtin_amdgcn_mfma_f32_16x16x32_bf16(af.v, B5, acc1, 0, 0, 0);
                acc2 = __builtin_amdgcn_mfma_f32_16x16x32_bf16(af.v, B6, acc2, 0, 0, 0);
                acc3 = __builtin_amdgcn_mfma_f32_16x16x32_bf16(af.v, B7, acc3, 0, 0, 0);
            }
        }
        // (3) rotate pipeline registers
        if (hasN) {
            A00 = nA00; A01 = nA01; A10 = nA10; A11 = nA11;
            B0 = nB0; B1 = nB1; B2 = nB2; B3 = nB3;
            B4 = nB4; B5 = nB5; B6 = nB6; B7 = nB7;
            T0 = nT0; T1 = nT1; T2v = nT2; T3v = nT3;
        }
    }

    // lsum: lanes {m, m+16, m+32, m+48} hold row-m partials for this wave's units
    lsum += __shfl_xor(lsum, 16);
    lsum += __shfl_xor(lsum, 32);

    // epilogue: wave w writes only its OWN accr region [w*1024, (w+1)*1024) —
    // disjoint per wave; cross-wave reads gated by the single barrier.
    *(f32x4*)&accr[((wave * 4 + 0) * 64 + lane) * 4] = acc0;
    *(f32x4*)&accr[((wave * 4 + 1) * 64 + lane) * 4] = acc1;
    *(f32x4*)&accr[((wave * 4 + 2) * 64 + lane) * 4] = acc2;
    *(f32x4*)&accr[((wave * 4 + 3) * 64 + lane) * 4] = acc3;
    if (lane < 16) sred[wave * 16 + lane] = lsum;
    __syncthreads();

    const int tile = wave;
    f32x4 tot = {0, 0, 0, 0};
#pragma unroll
    for (int w = 0; w < 4; ++w) {
        f32x4 c = *(const f32x4*)&accr[((w * 4 + tile) * 64 + lane) * 4];
        tot[0] += c[0]; tot[1] += c[1]; tot[2] += c[2]; tot[3] += c[3];
    }
#pragma unroll
    for (int r = 0; r < 4; ++r) {
        int row = quad * 4 + r;  // C/D: row=(lane>>4)*4+reg, col=l16 within tile
        float lv = sred[row] + sred[16 + row] + sred[32 + row] + sred[48 + row];
        float v = tot[r] / lv;
        out[(size_t)(i0 + row) * FOUT + tile * 16 + l16] =
            v > 0.f ? v : (exp2f(v * LOG2E) - 1.f);
    }
}

extern "C" void kernel_launch(void* const* d_in, const int* in_sizes, int n_in,
                              void* d_out, int out_size, void* d_ws, size_t ws_size,
                              hipStream_t stream) {
    const float* h   = (const float*)d_in[0];
    const float* adj = (const float*)d_in[1];
    const float* W   = (const float*)d_in[2];
    const float* a   = (const float*)d_in[3];
    float* out = (float*)d_out;

    char* base = (char*)d_ws;
    __hip_bfloat16* WhB = (__hip_bfloat16*)base;     base += (size_t)N * FOUT * 2;
    float* s2 = (float*)base;                        base += (size_t)N * 4;
    float* t2 = (float*)base;                        base += (size_t)N * 4 + 1024;
    unsigned* keys = (unsigned*)base;

    hipMemsetAsync(keys, 0, 2 * sizeof(unsigned), stream);
    k_prep<<<N / 32, 256, 0, stream>>>(h, W, a, WhB, s2, t2, keys);
    k_attn<<<N / 16, 256, 0, stream>>>(adj, WhB, s2, t2, keys, out);
}